// Round 13
// baseline (267.144 us; speedup 1.0000x reference)
//
#include <hip/hip_runtime.h>
#include <hip/hip_fp16.h>
#include <math.h>
#include <stdint.h>

#define N_NODES 100000
#define N_EDGES 1600000
#define N_TOT   (N_EDGES + N_NODES)   // edges + self-loops
#define NEG_SLOPE 0.2f

#define BKT   64                               // dst nodes per bucket
#define NBUCK ((N_NODES + BKT - 1) / BKT)      // 1563
#define NSUB  8                                // sub-streams per bucket (one per XCD)
#define CAP   320                              // slots per (bucket,sub); mean 128
#define WIN   (NSUB * CAP)                     // ssrc window per bucket (2560)

typedef int nt_int4 __attribute__((ext_vector_type(4)));   // native vec for nontemporal builtins

// ---------------- layer 1: node transform -------------------------------
// h1 = x @ W1; per-edge gather tables (h1, as1) fp16; ad1 fp32.
__global__ void k_node1(const float* __restrict__ x, const float* __restrict__ W1,
                        const float* __restrict__ a_src1, const float* __restrict__ a_dst1,
                        __half* __restrict__ h1h, __half* __restrict__ as1h,
                        float* __restrict__ ad1) {
    int tid  = blockIdx.x * blockDim.x + threadIdx.x;
    int n    = tid >> 3;
    int head = tid & 7;
    if (n >= N_NODES) return;

    float xv[5];
#pragma unroll
    for (int k = 0; k < 5; ++k) xv[k] = x[n * 5 + k];

    float hv[8];
    float as = 0.f, ad = 0.f;
#pragma unroll
    for (int j = 0; j < 8; ++j) {
        int c = head * 8 + j;
        float acc = 0.f;
#pragma unroll
        for (int k = 0; k < 5; ++k) acc += xv[k] * W1[k * 64 + c];
        hv[j] = acc;
        as += acc * a_src1[c];
        ad += acc * a_dst1[c];
    }
    __half2* hp = (__half2*)&h1h[(size_t)n * 64 + head * 8];
#pragma unroll
    for (int j = 0; j < 4; ++j)
        hp[j] = __halves2half2(__float2half(hv[2 * j]), __float2half(hv[2 * j + 1]));
    as1h[n * 8 + head] = __float2half(as);
    ad1[n * 8 + head] = ad;
}

// ---------------- stage 1: bucket partition (edges only) ----------------
// 4 edges/thread. Sub-stream routed by the REAL XCD id (s_getreg HW_REG_XCC_ID)
// so each substream's cache lines are written by exactly one XCD's L2 and
// flush as full 64B lines. Self-loops are synthesized in k_scatter2.
__global__ void k_part(const int* __restrict__ src, const int* __restrict__ dst,
                       int* __restrict__ subcnt, unsigned* __restrict__ pairs) {
    int g = blockIdx.x * blockDim.x + threadIdx.x;
    int base = g * 4;
    if (base >= N_EDGES) return;
    nt_int4 s4 = __builtin_nontemporal_load((const nt_int4*)(src + base));
    nt_int4 d4 = __builtin_nontemporal_load((const nt_int4*)(dst + base));
    unsigned xcc;
    asm volatile("s_getreg_b32 %0, hwreg(HW_REG_XCC_ID)" : "=s"(xcc));
    xcc &= 7;
#pragma unroll
    for (int i = 0; i < 4; ++i) {
        int s = s4[i], d = d4[i];
        int sub = (d >> 6) * NSUB + (int)xcc;
        int idx = atomicAdd(&subcnt[sub], 1);
        if (idx < CAP)
            pairs[(size_t)sub * CAP + idx] = ((unsigned)(d & 63) << 17) | (unsigned)s;
    }
}

// ---------------- stage 2: bucket-local CSR scatter ---------------------
// Block per bucket. Self-loops synthesized here: lcnt pre-seeded with 1,
// slot 0 of each dst holds its own id. LDS histogram + 64-lane shuffle
// scan, scatter into the bucket's strided window (b*WIN).
__global__ void __launch_bounds__(256) k_scatter2(
        const int* __restrict__ subcnt, const unsigned* __restrict__ pairs,
        int* __restrict__ rbeg, int* __restrict__ rend, int* __restrict__ ssrc) {
    __shared__ int lcnt[64], lofs[64], lcur[64];
    __shared__ int scnt[NSUB];
    int b = blockIdx.x, tid = threadIdx.x;

    if (tid < 64) {
        int gi = b * 64 + tid;
        lcnt[tid] = (gi < N_NODES) ? 1 : 0;   // self-loop pre-count
        lcur[tid] = 1;                        // slot 0 = self-loop
    }
    if (tid < NSUB) scnt[tid] = min(subcnt[b * NSUB + tid], CAP);
    __syncthreads();

    for (int ss = 0; ss < NSUB; ++ss) {
        int cnt = scnt[ss];
        const unsigned* pp = pairs + (size_t)(b * NSUB + ss) * CAP;
        for (int k = tid; k < cnt; k += 256) atomicAdd(&lcnt[pp[k] >> 17], 1);
    }
    __syncthreads();

    if (tid < 64) {
        int v  = lcnt[tid];
        int sc = v;
#pragma unroll
        for (int off = 1; off < 64; off <<= 1) {
            int u = __shfl_up(sc, off, 64);
            if (tid >= off) sc += u;
        }
        int ex = sc - v;                 // exclusive prefix
        lofs[tid] = ex;
        int gi = b * 64 + tid;
        if (gi < N_NODES) {
            rbeg[gi] = b * WIN + ex;
            rend[gi] = b * WIN + ex + v;
            ssrc[b * WIN + ex] = gi;     // self-loop record
        }
    }
    __syncthreads();

    int base = b * WIN;
    for (int ss = 0; ss < NSUB; ++ss) {
        int cnt = scnt[ss];
        const unsigned* pp = pairs + (size_t)(b * NSUB + ss) * CAP;
        for (int k = tid; k < cnt; k += 256) {
            unsigned p = pp[k];
            int dl = p >> 17;
            int idx = atomicAdd(&lcur[dl], 1);
            ssrc[base + lofs[dl] + idx] = (int)(p & 0x1FFFF);
        }
    }
}

// ---------------- layer 1 gather + softmax + ELU + fused node2 ----------
// One wave per dst. Half-wave = edge (ed=lane>>5), lane covers 2 channels
// via one __half2 load: every ALU instruction processes TWO edges.
__global__ void __launch_bounds__(256) k_gather1(
        const int* __restrict__ rbeg, const int* __restrict__ rend,
        const int* __restrict__ ssrc, const __half2* __restrict__ h1h2,
        const __half* __restrict__ as1h, const float* __restrict__ ad1,
        const float* __restrict__ b1, const float* __restrict__ W2,
        const float* __restrict__ a_src2, const float* __restrict__ a_dst2,
        float4* __restrict__ rec) {
    int gtid = blockIdx.x * blockDim.x + threadIdx.x;
    int d    = gtid >> 6;
    int lane = threadIdx.x & 63;
    if (d >= N_NODES) return;
    int ed   = lane >> 5;      // which edge of the pair this half-wave owns
    int l    = lane & 31;      // channel-pair index (channels 2l, 2l+1)
    int head = l >> 2;

    int beg = rbeg[d], end = rend[d];
    float adv = ad1[d * 8 + head];
    float nx = 0.f, ny = 0.f, den = 0.f;

    int k = beg;
    for (; k + 4 <= end; k += 4) {            // 2 pair-iterations in flight
        int sA = ssrc[k + ed];
        int sB = ssrc[k + 2 + ed];
        float aA = __half2float(as1h[sA * 8 + head]);
        float aB = __half2float(as1h[sB * 8 + head]);
        float2 hA = __half22float2(h1h2[(size_t)sA * 32 + l]);
        float2 hB = __half22float2(h1h2[(size_t)sB * 32 + l]);
        float tA = aA + adv; tA = fmaxf(tA, NEG_SLOPE * tA);
        float tB = aB + adv; tB = fmaxf(tB, NEG_SLOPE * tB);
        float wA = __expf(tA), wB = __expf(tB);
        nx += wA * hA.x + wB * hB.x;
        ny += wA * hA.y + wB * hB.y;
        den += wA + wB;
    }
    for (; k + 2 <= end; k += 2) {
        int s = ssrc[k + ed];
        float a = __half2float(as1h[s * 8 + head]);
        float2 h = __half22float2(h1h2[(size_t)s * 32 + l]);
        float t = a + adv; t = fmaxf(t, NEG_SLOPE * t);
        float w = __expf(t);
        nx += w * h.x; ny += w * h.y; den += w;
    }
    if (k < end) {                             // odd tail: half-wave 0 only
        int s = ssrc[k];
        float a = __half2float(as1h[s * 8 + head]);
        float2 h = __half22float2(h1h2[(size_t)s * 32 + l]);
        float t = a + adv; t = fmaxf(t, NEG_SLOPE * t);
        float w = (ed == 0) ? __expf(t) : 0.f;
        nx += w * h.x; ny += w * h.y; den += w;
    }
    // merge the two half-wave partial sums
    nx  += __shfl_xor(nx, 32, 64);
    ny  += __shfl_xor(ny, 32, 64);
    den += __shfl_xor(den, 32, 64);

    float inv = 1.f / den;                     // den>0 (self-loop guarantees)
    float v0 = nx * inv + b1[2 * l];
    float v1 = ny * inv + b1[2 * l + 1];
    v0 = (v0 > 0.f) ? v0 : (__expf(v0) - 1.f); // ELU
    v1 = (v1 > 0.f) ? v1 : (__expf(v1) - 1.f);

    // fused layer-2 transform: h2 = sum_c v_c * W2[c,:]
    float h20 = v0 * W2[4 * l]     + v1 * W2[4 * l + 2];
    float h21 = v0 * W2[4 * l + 1] + v1 * W2[4 * l + 3];
#pragma unroll
    for (int off = 16; off; off >>= 1) {
        h20 += __shfl_xor(h20, off, 32);
        h21 += __shfl_xor(h21, off, 32);
    }
    if (lane == 0) {
        float as2v = h20 * a_src2[0] + h21 * a_src2[1];
        float ad2v = h20 * a_dst2[0] + h21 * a_dst2[1];
        rec[d] = make_float4(h20, h21, as2v, ad2v);
    }
}

// ---------------- layer 2: per-dst gather + log_softmax -----------------
// 16 lanes per dst node; lanes stride the edge list (x2 unrolled).
__global__ void k_gather2(const int* __restrict__ rbeg, const int* __restrict__ rend,
                          const int* __restrict__ ssrc, const float4* __restrict__ rec,
                          const float* __restrict__ b2, float* __restrict__ out) {
    int gtid = blockIdx.x * blockDim.x + threadIdx.x;
    int d    = gtid >> 4;
    int lane = gtid & 15;
    if (d >= N_NODES) return;

    int beg = rbeg[d], end = rend[d];
    float adv = rec[d].w;
    float n0 = 0.f, n1 = 0.f, den = 0.f;
    int k = beg + lane;
    for (; k + 16 < end; k += 32) {
        int s0 = ssrc[k], s1 = ssrc[k + 16];
        float4 r0 = rec[s0];
        float4 r1 = rec[s1];
        float t0 = r0.z + adv; t0 = fmaxf(t0, NEG_SLOPE * t0);
        float t1 = r1.z + adv; t1 = fmaxf(t1, NEG_SLOPE * t1);
        float w0 = __expf(t0), w1 = __expf(t1);
        n0 += w0 * r0.x + w1 * r1.x;
        n1 += w0 * r0.y + w1 * r1.y;
        den += w0 + w1;
    }
    if (k < end) {
        int s = ssrc[k];
        float4 r = rec[s];
        float t = r.z + adv; t = fmaxf(t, NEG_SLOPE * t);
        float w = __expf(t);
        n0 += w * r.x; n1 += w * r.y; den += w;
    }
#pragma unroll
    for (int off = 8; off; off >>= 1) {
        n0  += __shfl_xor(n0,  off, 16);
        n1  += __shfl_xor(n1,  off, 16);
        den += __shfl_xor(den, off, 16);
    }
    if (lane == 0) {
        float o0 = n0 / den + b2[0];
        float o1 = n1 / den + b2[1];
        float m  = fmaxf(o0, o1);
        float lse = m + __logf(__expf(o0 - m) + __expf(o1 - m));
        out[d * 2 + 0] = o0 - lse;
        out[d * 2 + 1] = o1 - lse;
    }
}

extern "C" void kernel_launch(void* const* d_in, const int* in_sizes, int n_in,
                              void* d_out, int out_size, void* d_ws, size_t ws_size,
                              hipStream_t stream) {
    const float* x      = (const float*)d_in[0];
    const int*   ei     = (const int*)d_in[1];     // [2, E] int32
    const float* W1     = (const float*)d_in[2];
    const float* a_src1 = (const float*)d_in[3];
    const float* a_dst1 = (const float*)d_in[4];
    const float* b1     = (const float*)d_in[5];
    const float* W2     = (const float*)d_in[6];
    const float* a_src2 = (const float*)d_in[7];
    const float* a_dst2 = (const float*)d_in[8];
    const float* b2     = (const float*)d_in[9];
    float* out = (float*)d_out;

    const int* src = ei;
    const int* dst = ei + N_EDGES;

    // ---- workspace layout (~53 MB) ----
    int* subcnt = (int*)d_ws;                                   // NBUCK*NSUB
    int* rbeg   = subcnt + NBUCK * NSUB;                        // N
    int* rend   = rbeg + N_NODES;                               // N
    int* ssrc   = rend + N_NODES;                               // NBUCK*WIN (16 MB)
    uintptr_t pp = ((uintptr_t)(ssrc + (size_t)NBUCK * WIN) + 255) & ~(uintptr_t)255;
    float4*   rec   = (float4*)pp;                              // N float4   (1.6 MB)
    unsigned* pairs = (unsigned*)(rec + N_NODES);               // NBUCK*NSUB*CAP (16 MB)
    float*    ad1   = (float*)(pairs + (size_t)NBUCK * NSUB * CAP); // N*8 fp32 (3.2 MB)
    __half*   h1h   = (__half*)(ad1 + (size_t)N_NODES * 8);     // N*64 fp16 (12.8 MB)
    __half*   as1h  = h1h + (size_t)N_NODES * 64;               // N*8 fp16 (1.6 MB)

    (void)hipMemsetAsync(subcnt, 0, (size_t)NBUCK * NSUB * sizeof(int), stream);

    k_node1<<<(N_NODES * 8 + 255) / 256, 256, 0, stream>>>(x, W1, a_src1, a_dst1,
                                                           h1h, as1h, ad1);
    k_part<<<(N_EDGES / 4 + 255) / 256, 256, 0, stream>>>(src, dst, subcnt, pairs);
    k_scatter2<<<NBUCK, 256, 0, stream>>>(subcnt, pairs, rbeg, rend, ssrc);
    k_gather1<<<(N_NODES * 64 + 255) / 256, 256, 0, stream>>>(rbeg, rend, ssrc,
                                                              (const __half2*)h1h,
                                                              as1h, ad1, b1, W2,
                                                              a_src2, a_dst2, rec);
    k_gather2<<<(N_NODES * 16 + 255) / 256, 256, 0, stream>>>(rbeg, rend, ssrc,
                                                              rec, b2, out);
}

// Round 14
// 214.297 us; speedup vs baseline: 1.2466x; 1.2466x over previous
//
#include <hip/hip_runtime.h>
#include <hip/hip_fp16.h>
#include <math.h>
#include <stdint.h>

#define N_NODES 100000
#define N_EDGES 1600000
#define N_TOT   (N_EDGES + N_NODES)   // edges + self-loops
#define NEG_SLOPE 0.2f

#define CB     512                            // dst nodes per coarse bucket
#define CBBITS 9
#define NCB    ((N_NODES + CB - 1) / CB)      // 196 coarse buckets
#define TP     4096                           // edges per partition block
#define NPB    ((N_EDGES + TP - 1) / TP)      // 391 partition blocks

typedef int nt_int4 __attribute__((ext_vector_type(4)));

// ---------------- layer 1: node transform -------------------------------
__global__ void k_node1(const float* __restrict__ x, const float* __restrict__ W1,
                        const float* __restrict__ a_src1, const float* __restrict__ a_dst1,
                        __half* __restrict__ h1h, __half* __restrict__ as1h,
                        float* __restrict__ ad1) {
    int tid  = blockIdx.x * blockDim.x + threadIdx.x;
    int n    = tid >> 3;
    int head = tid & 7;
    if (n >= N_NODES) return;

    float xv[5];
#pragma unroll
    for (int k = 0; k < 5; ++k) xv[k] = x[n * 5 + k];

    float hv[8];
    float as = 0.f, ad = 0.f;
#pragma unroll
    for (int j = 0; j < 8; ++j) {
        int c = head * 8 + j;
        float acc = 0.f;
#pragma unroll
        for (int k = 0; k < 5; ++k) acc += xv[k] * W1[k * 64 + c];
        hv[j] = acc;
        as += acc * a_src1[c];
        ad += acc * a_dst1[c];
    }
    __half2* hp = (__half2*)&h1h[(size_t)n * 64 + head * 8];
#pragma unroll
    for (int j = 0; j < 4; ++j)
        hp[j] = __halves2half2(__float2half(hv[2 * j]), __float2half(hv[2 * j + 1]));
    as1h[n * 8 + head] = __float2half(as);
    ad1[n * 8 + head] = ad;
}

// ---------------- partition pass A: per-block LDS histogram -------------
// Zero global atomics: each block writes its private cnt[blk][bin] row.
__global__ void __launch_bounds__(256) k_partA(const int* __restrict__ dst,
                                               int* __restrict__ cnt) {
    __shared__ int lcnt[NCB];
    int blk = blockIdx.x, t = threadIdx.x;
    if (t < NCB) lcnt[t] = 0;
    __syncthreads();
    int base = blk * TP + t * 16;
    if (base < N_EDGES) {
#pragma unroll
        for (int i = 0; i < 4; ++i) {
            nt_int4 d4 = __builtin_nontemporal_load((const nt_int4*)(dst + base + i * 4));
#pragma unroll
            for (int j = 0; j < 4; ++j) atomicAdd(&lcnt[d4[j] >> CBBITS], 1);
        }
    }
    __syncthreads();
    if (t < NCB) cnt[blk * NCB + t] = lcnt[t];
}

// ---------------- s1: per-bin totals ------------------------------------
__global__ void __launch_bounds__(256) k_s1(const int* __restrict__ cnt,
                                            int* __restrict__ tots) {
    __shared__ int sm[256];
    int B = blockIdx.x, t = threadIdx.x;
    int s = 0;
    for (int blk = t; blk < NPB; blk += 256) s += cnt[blk * NCB + B];
    sm[t] = s;
    __syncthreads();
    for (int off = 128; off; off >>= 1) {
        if (t < off) sm[t] += sm[t + off];
        __syncthreads();
    }
    if (t == 0) tots[B] = sm[0];
}

// ---------------- s2: chunk bases cb[blk][bin] + bucket starts ----------
__global__ void __launch_bounds__(512) k_s2(const int* __restrict__ cnt,
                                            const int* __restrict__ tots,
                                            int* __restrict__ cb,
                                            int* __restrict__ bstart) {
    __shared__ int sm[512];
    __shared__ int tt[NCB];
    __shared__ int mybase_s;
    int B = blockIdx.x, t = threadIdx.x;
    if (t < NCB) tt[t] = tots[t];
    int v = (t < NPB) ? cnt[t * NCB + B] : 0;
    sm[t] = v;
    __syncthreads();
    if (t == 0) {
        int run = 0;
        for (int i = 0; i < B; ++i) run += tt[i];
        mybase_s = run;
        bstart[B] = run;
    }
    for (int off = 1; off < 512; off <<= 1) {       // inclusive doubling scan
        int u = (t >= off) ? sm[t - off] : 0;
        __syncthreads();
        sm[t] += u;
        __syncthreads();
    }
    if (t < NPB) cb[t * NCB + B] = mybase_s + sm[t] - v;
}

// ---------------- partition pass B: cursor scatter (no global atomics) --
__global__ void __launch_bounds__(256) k_partB(const int* __restrict__ src,
                                               const int* __restrict__ dst,
                                               const int* __restrict__ cb,
                                               unsigned* __restrict__ pairs) {
    __shared__ int lcur[NCB], cbl[NCB];
    int blk = blockIdx.x, t = threadIdx.x;
    if (t < NCB) { lcur[t] = 0; cbl[t] = cb[blk * NCB + t]; }
    __syncthreads();
    int base = blk * TP + t * 16;
    if (base < N_EDGES) {
#pragma unroll
        for (int i = 0; i < 4; ++i) {
            nt_int4 s4 = __builtin_nontemporal_load((const nt_int4*)(src + base + i * 4));
            nt_int4 d4 = __builtin_nontemporal_load((const nt_int4*)(dst + base + i * 4));
#pragma unroll
            for (int j = 0; j < 4; ++j) {
                int d = d4[j], s = s4[j];
                int bin = d >> CBBITS;
                int idx = atomicAdd(&lcur[bin], 1);
                pairs[cbl[bin] + idx] = ((unsigned)(d & (CB - 1)) << 17) | (unsigned)s;
            }
        }
    }
}

// ---------------- bucket-local CSR build --------------------------------
// Block per coarse bucket (512 dsts). Contiguous pairs reads; histogram +
// shuffle scan; self-loops synthesized (preseed 1, slot 0 = own id).
__global__ void __launch_bounds__(256) k_scatter3(
        const unsigned* __restrict__ pairs, const int* __restrict__ bstart,
        const int* __restrict__ tots, int* __restrict__ rbeg,
        int* __restrict__ rend, int* __restrict__ ssrc) {
    __shared__ int lcnt[CB], lofs[CB], lcur[CB];
    __shared__ int wsum[4];
    int B = blockIdx.x, t = threadIdx.x;
    int nvalid = min(CB, N_NODES - B * CB);
    int m = tots[B];
    int ibase = bstart[B];
    int obase = ibase + B * CB;   // + self-loops of all previous (full) buckets

    lcnt[t]       = (t < nvalid) ? 1 : 0;
    lcnt[t + 256] = (t + 256 < nvalid) ? 1 : 0;
    lcur[t] = 1; lcur[t + 256] = 1;
    __syncthreads();

    for (int k = t; k < m; k += 256)
        atomicAdd(&lcnt[pairs[ibase + k] >> 17], 1);
    __syncthreads();

    // exclusive scan over 512 bins, 2 bins/thread
    int a = lcnt[2 * t], bq = lcnt[2 * t + 1];
    int v = a + bq;
    int ln = t & 63, wv = t >> 6;
    int sc = v;
#pragma unroll
    for (int off = 1; off < 64; off <<= 1) {
        int u = __shfl_up(sc, off, 64);
        if (ln >= off) sc += u;
    }
    if (ln == 63) wsum[wv] = sc;
    __syncthreads();
    int wbase = 0;
#pragma unroll
    for (int i = 0; i < 4; ++i) if (i < wv) wbase += wsum[i];
    int ex = wbase + sc - v;
    lofs[2 * t] = ex;
    lofs[2 * t + 1] = ex + a;

    int gi0 = B * CB + 2 * t, gi1 = gi0 + 1;
    if (gi0 < N_NODES) {
        rbeg[gi0] = obase + ex;
        rend[gi0] = obase + ex + a;
        ssrc[obase + ex] = gi0;            // self-loop record, slot 0
    }
    if (gi1 < N_NODES) {
        rbeg[gi1] = obase + ex + a;
        rend[gi1] = obase + ex + a + bq;
        ssrc[obase + ex + a] = gi1;
    }
    __syncthreads();

    for (int k = t; k < m; k += 256) {
        unsigned p = pairs[ibase + k];
        int dl = p >> 17;
        int idx = atomicAdd(&lcur[dl], 1);
        ssrc[obase + lofs[dl] + idx] = (int)(p & 0x1FFFF);
    }
}

// ---------------- layer 1 gather + softmax + ELU + fused node2 ----------
__global__ void __launch_bounds__(256) k_gather1(
        const int* __restrict__ rbeg, const int* __restrict__ rend,
        const int* __restrict__ ssrc, const __half2* __restrict__ h1h2,
        const __half* __restrict__ as1h, const float* __restrict__ ad1,
        const float* __restrict__ b1, const float* __restrict__ W2,
        const float* __restrict__ a_src2, const float* __restrict__ a_dst2,
        float4* __restrict__ rec) {
    int gtid = blockIdx.x * blockDim.x + threadIdx.x;
    int d    = gtid >> 6;
    int lane = threadIdx.x & 63;
    if (d >= N_NODES) return;
    int ed   = lane >> 5;
    int l    = lane & 31;
    int head = l >> 2;

    int beg = rbeg[d], end = rend[d];
    float adv = ad1[d * 8 + head];
    float nx = 0.f, ny = 0.f, den = 0.f;

    int k = beg;
    for (; k + 4 <= end; k += 4) {
        int sA = ssrc[k + ed];
        int sB = ssrc[k + 2 + ed];
        float aA = __half2float(as1h[sA * 8 + head]);
        float aB = __half2float(as1h[sB * 8 + head]);
        float2 hA = __half22float2(h1h2[(size_t)sA * 32 + l]);
        float2 hB = __half22float2(h1h2[(size_t)sB * 32 + l]);
        float tA = aA + adv; tA = fmaxf(tA, NEG_SLOPE * tA);
        float tB = aB + adv; tB = fmaxf(tB, NEG_SLOPE * tB);
        float wA = __expf(tA), wB = __expf(tB);
        nx += wA * hA.x + wB * hB.x;
        ny += wA * hA.y + wB * hB.y;
        den += wA + wB;
    }
    for (; k + 2 <= end; k += 2) {
        int s = ssrc[k + ed];
        float a = __half2float(as1h[s * 8 + head]);
        float2 h = __half22float2(h1h2[(size_t)s * 32 + l]);
        float t = a + adv; t = fmaxf(t, NEG_SLOPE * t);
        float w = __expf(t);
        nx += w * h.x; ny += w * h.y; den += w;
    }
    if (k < end) {
        int s = ssrc[k];
        float a = __half2float(as1h[s * 8 + head]);
        float2 h = __half22float2(h1h2[(size_t)s * 32 + l]);
        float t = a + adv; t = fmaxf(t, NEG_SLOPE * t);
        float w = (ed == 0) ? __expf(t) : 0.f;
        nx += w * h.x; ny += w * h.y; den += w;
    }
    nx  += __shfl_xor(nx, 32, 64);
    ny  += __shfl_xor(ny, 32, 64);
    den += __shfl_xor(den, 32, 64);

    float inv = 1.f / den;
    float v0 = nx * inv + b1[2 * l];
    float v1 = ny * inv + b1[2 * l + 1];
    v0 = (v0 > 0.f) ? v0 : (__expf(v0) - 1.f);
    v1 = (v1 > 0.f) ? v1 : (__expf(v1) - 1.f);

    float h20 = v0 * W2[4 * l]     + v1 * W2[4 * l + 2];
    float h21 = v0 * W2[4 * l + 1] + v1 * W2[4 * l + 3];
#pragma unroll
    for (int off = 16; off; off >>= 1) {
        h20 += __shfl_xor(h20, off, 32);
        h21 += __shfl_xor(h21, off, 32);
    }
    if (lane == 0) {
        float as2v = h20 * a_src2[0] + h21 * a_src2[1];
        float ad2v = h20 * a_dst2[0] + h21 * a_dst2[1];
        rec[d] = make_float4(h20, h21, as2v, ad2v);
    }
}

// ---------------- layer 2: per-dst gather + log_softmax -----------------
__global__ void k_gather2(const int* __restrict__ rbeg, const int* __restrict__ rend,
                          const int* __restrict__ ssrc, const float4* __restrict__ rec,
                          const float* __restrict__ b2, float* __restrict__ out) {
    int gtid = blockIdx.x * blockDim.x + threadIdx.x;
    int d    = gtid >> 4;
    int lane = gtid & 15;
    if (d >= N_NODES) return;

    int beg = rbeg[d], end = rend[d];
    float adv = rec[d].w;
    float n0 = 0.f, n1 = 0.f, den = 0.f;
    int k = beg + lane;
    for (; k + 16 < end; k += 32) {
        int s0 = ssrc[k], s1 = ssrc[k + 16];
        float4 r0 = rec[s0];
        float4 r1 = rec[s1];
        float t0 = r0.z + adv; t0 = fmaxf(t0, NEG_SLOPE * t0);
        float t1 = r1.z + adv; t1 = fmaxf(t1, NEG_SLOPE * t1);
        float w0 = __expf(t0), w1 = __expf(t1);
        n0 += w0 * r0.x + w1 * r1.x;
        n1 += w0 * r0.y + w1 * r1.y;
        den += w0 + w1;
    }
    if (k < end) {
        int s = ssrc[k];
        float4 r = rec[s];
        float t = r.z + adv; t = fmaxf(t, NEG_SLOPE * t);
        float w = __expf(t);
        n0 += w * r.x; n1 += w * r.y; den += w;
    }
#pragma unroll
    for (int off = 8; off; off >>= 1) {
        n0  += __shfl_xor(n0,  off, 16);
        n1  += __shfl_xor(n1,  off, 16);
        den += __shfl_xor(den, off, 16);
    }
    if (lane == 0) {
        float o0 = n0 / den + b2[0];
        float o1 = n1 / den + b2[1];
        float m  = fmaxf(o0, o1);
        float lse = m + __logf(__expf(o0 - m) + __expf(o1 - m));
        out[d * 2 + 0] = o0 - lse;
        out[d * 2 + 1] = o1 - lse;
    }
}

extern "C" void kernel_launch(void* const* d_in, const int* in_sizes, int n_in,
                              void* d_out, int out_size, void* d_ws, size_t ws_size,
                              hipStream_t stream) {
    const float* x      = (const float*)d_in[0];
    const int*   ei     = (const int*)d_in[1];     // [2, E] int32
    const float* W1     = (const float*)d_in[2];
    const float* a_src1 = (const float*)d_in[3];
    const float* a_dst1 = (const float*)d_in[4];
    const float* b1     = (const float*)d_in[5];
    const float* W2     = (const float*)d_in[6];
    const float* a_src2 = (const float*)d_in[7];
    const float* a_dst2 = (const float*)d_in[8];
    const float* b2     = (const float*)d_in[9];
    float* out = (float*)d_out;

    const int* src = ei;
    const int* dst = ei + N_EDGES;

    // ---- workspace layout (~34 MB), everything fully written before read:
    // no memset required.
    int* cnt    = (int*)d_ws;                                   // NPB*NCB
    int* cb     = cnt + NPB * NCB;                              // NPB*NCB
    int* tots   = cb + NPB * NCB;                               // NCB
    int* bstart = tots + NCB;                                   // NCB
    int* rbeg   = bstart + NCB;                                 // N
    int* rend   = rbeg + N_NODES;                               // N
    unsigned* pairs = (unsigned*)(rend + N_NODES);              // E (6.4 MB)
    int* ssrc   = (int*)(pairs + N_EDGES);                      // E+N (6.8 MB)
    uintptr_t pp = ((uintptr_t)(ssrc + N_TOT) + 255) & ~(uintptr_t)255;
    float4*   rec  = (float4*)pp;                               // N float4
    float*    ad1  = (float*)(rec + N_NODES);                   // N*8 fp32
    __half*   h1h  = (__half*)(ad1 + (size_t)N_NODES * 8);      // N*64 fp16
    __half*   as1h = h1h + (size_t)N_NODES * 64;                // N*8 fp16

    k_node1<<<(N_NODES * 8 + 255) / 256, 256, 0, stream>>>(x, W1, a_src1, a_dst1,
                                                           h1h, as1h, ad1);
    k_partA<<<NPB, 256, 0, stream>>>(dst, cnt);
    k_s1<<<NCB, 256, 0, stream>>>(cnt, tots);
    k_s2<<<NCB, 512, 0, stream>>>(cnt, tots, cb, bstart);
    k_partB<<<NPB, 256, 0, stream>>>(src, dst, cb, pairs);
    k_scatter3<<<NCB, 256, 0, stream>>>(pairs, bstart, tots, rbeg, rend, ssrc);
    k_gather1<<<(N_NODES * 64 + 255) / 256, 256, 0, stream>>>(rbeg, rend, ssrc,
                                                              (const __half2*)h1h,
                                                              as1h, ad1, b1, W2,
                                                              a_src2, a_dst2, rec);
    k_gather2<<<(N_NODES * 16 + 255) / 256, 256, 0, stream>>>(rbeg, rend, ssrc,
                                                              rec, b2, out);
}

// Round 15
// 200.349 us; speedup vs baseline: 1.3334x; 1.0696x over previous
//
#include <hip/hip_runtime.h>
#include <hip/hip_fp16.h>
#include <math.h>
#include <stdint.h>

#define N_NODES 100000
#define N_EDGES 1600000
#define N_TOT   (N_EDGES + N_NODES)   // edges + self-loops
#define NEG_SLOPE 0.2f

#define CB     512                            // dst nodes per coarse bucket
#define CBBITS 9
#define NCB    ((N_NODES + CB - 1) / CB)      // 196 coarse buckets
#define TP     4096                           // edges per partition block
#define NPB    ((N_EDGES + TP - 1) / TP)      // 391 partition blocks

typedef int nt_int4 __attribute__((ext_vector_type(4)));

// ---------------- layer 1: node transform -------------------------------
__global__ void k_node1(const float* __restrict__ x, const float* __restrict__ W1,
                        const float* __restrict__ a_src1, const float* __restrict__ a_dst1,
                        __half* __restrict__ h1h, __half* __restrict__ as1h,
                        float* __restrict__ ad1) {
    int tid  = blockIdx.x * blockDim.x + threadIdx.x;
    int n    = tid >> 3;
    int head = tid & 7;
    if (n >= N_NODES) return;

    float xv[5];
#pragma unroll
    for (int k = 0; k < 5; ++k) xv[k] = x[n * 5 + k];

    float hv[8];
    float as = 0.f, ad = 0.f;
#pragma unroll
    for (int j = 0; j < 8; ++j) {
        int c = head * 8 + j;
        float acc = 0.f;
#pragma unroll
        for (int k = 0; k < 5; ++k) acc += xv[k] * W1[k * 64 + c];
        hv[j] = acc;
        as += acc * a_src1[c];
        ad += acc * a_dst1[c];
    }
    __half2* hp = (__half2*)&h1h[(size_t)n * 64 + head * 8];
#pragma unroll
    for (int j = 0; j < 4; ++j)
        hp[j] = __halves2half2(__float2half(hv[2 * j]), __float2half(hv[2 * j + 1]));
    as1h[n * 8 + head] = __float2half(as);
    ad1[n * 8 + head] = ad;
}

// ---------------- partition pass A: per-block LDS histogram -------------
__global__ void __launch_bounds__(256) k_partA(const int* __restrict__ dst,
                                               int* __restrict__ cnt) {
    __shared__ int lcnt[NCB];
    int blk = blockIdx.x, t = threadIdx.x;
    if (t < NCB) lcnt[t] = 0;
    __syncthreads();
    int base = blk * TP + t * 16;
    if (base < N_EDGES) {
#pragma unroll
        for (int i = 0; i < 4; ++i) {
            nt_int4 d4 = __builtin_nontemporal_load((const nt_int4*)(dst + base + i * 4));
#pragma unroll
            for (int j = 0; j < 4; ++j) atomicAdd(&lcnt[d4[j] >> CBBITS], 1);
        }
    }
    __syncthreads();
    if (t < NCB) cnt[blk * NCB + t] = lcnt[t];
}

// ---------------- s1: per-bin totals ------------------------------------
__global__ void __launch_bounds__(256) k_s1(const int* __restrict__ cnt,
                                            int* __restrict__ tots) {
    __shared__ int sm[256];
    int B = blockIdx.x, t = threadIdx.x;
    int s = 0;
    for (int blk = t; blk < NPB; blk += 256) s += cnt[blk * NCB + B];
    sm[t] = s;
    __syncthreads();
    for (int off = 128; off; off >>= 1) {
        if (t < off) sm[t] += sm[t + off];
        __syncthreads();
    }
    if (t == 0) tots[B] = sm[0];
}

// ---------------- s2: chunk bases cb[blk][bin] + bucket starts ----------
__global__ void __launch_bounds__(512) k_s2(const int* __restrict__ cnt,
                                            const int* __restrict__ tots,
                                            int* __restrict__ cb,
                                            int* __restrict__ bstart) {
    __shared__ int sm[512];
    __shared__ int tt[NCB];
    __shared__ int mybase_s;
    int B = blockIdx.x, t = threadIdx.x;
    if (t < NCB) tt[t] = tots[t];
    int v = (t < NPB) ? cnt[t * NCB + B] : 0;
    sm[t] = v;
    __syncthreads();
    if (t == 0) {
        int run = 0;
        for (int i = 0; i < B; ++i) run += tt[i];
        mybase_s = run;
        bstart[B] = run;
    }
    for (int off = 1; off < 512; off <<= 1) {       // inclusive doubling scan
        int u = (t >= off) ? sm[t - off] : 0;
        __syncthreads();
        sm[t] += u;
        __syncthreads();
    }
    if (t < NPB) cb[t * NCB + B] = mybase_s + sm[t] - v;
}

// ---------------- partition pass B: cursor scatter (no global atomics) --
__global__ void __launch_bounds__(256) k_partB(const int* __restrict__ src,
                                               const int* __restrict__ dst,
                                               const int* __restrict__ cb,
                                               unsigned* __restrict__ pairs) {
    __shared__ int lcur[NCB], cbl[NCB];
    int blk = blockIdx.x, t = threadIdx.x;
    if (t < NCB) { lcur[t] = 0; cbl[t] = cb[blk * NCB + t]; }
    __syncthreads();
    int base = blk * TP + t * 16;
    if (base < N_EDGES) {
#pragma unroll
        for (int i = 0; i < 4; ++i) {
            nt_int4 s4 = __builtin_nontemporal_load((const nt_int4*)(src + base + i * 4));
            nt_int4 d4 = __builtin_nontemporal_load((const nt_int4*)(dst + base + i * 4));
#pragma unroll
            for (int j = 0; j < 4; ++j) {
                int d = d4[j], s = s4[j];
                int bin = d >> CBBITS;
                int idx = atomicAdd(&lcur[bin], 1);
                pairs[cbl[bin] + idx] = ((unsigned)(d & (CB - 1)) << 17) | (unsigned)s;
            }
        }
    }
}

// ---------------- bucket-local CSR build --------------------------------
__global__ void __launch_bounds__(256) k_scatter3(
        const unsigned* __restrict__ pairs, const int* __restrict__ bstart,
        const int* __restrict__ tots, int* __restrict__ rbeg,
        int* __restrict__ rend, int* __restrict__ ssrc) {
    __shared__ int lcnt[CB], lofs[CB], lcur[CB];
    __shared__ int wsum[4];
    int B = blockIdx.x, t = threadIdx.x;
    int nvalid = min(CB, N_NODES - B * CB);
    int m = tots[B];
    int ibase = bstart[B];
    int obase = ibase + B * CB;   // + self-loops of all previous (full) buckets

    lcnt[t]       = (t < nvalid) ? 1 : 0;
    lcnt[t + 256] = (t + 256 < nvalid) ? 1 : 0;
    lcur[t] = 1; lcur[t + 256] = 1;
    __syncthreads();

    for (int k = t; k < m; k += 256)
        atomicAdd(&lcnt[pairs[ibase + k] >> 17], 1);
    __syncthreads();

    // exclusive scan over 512 bins, 2 bins/thread
    int a = lcnt[2 * t], bq = lcnt[2 * t + 1];
    int v = a + bq;
    int ln = t & 63, wv = t >> 6;
    int sc = v;
#pragma unroll
    for (int off = 1; off < 64; off <<= 1) {
        int u = __shfl_up(sc, off, 64);
        if (ln >= off) sc += u;
    }
    if (ln == 63) wsum[wv] = sc;
    __syncthreads();
    int wbase = 0;
#pragma unroll
    for (int i = 0; i < 4; ++i) if (i < wv) wbase += wsum[i];
    int ex = wbase + sc - v;
    lofs[2 * t] = ex;
    lofs[2 * t + 1] = ex + a;

    int gi0 = B * CB + 2 * t, gi1 = gi0 + 1;
    if (gi0 < N_NODES) {
        rbeg[gi0] = obase + ex;
        rend[gi0] = obase + ex + a;
        ssrc[obase + ex] = gi0;            // self-loop record, slot 0
    }
    if (gi1 < N_NODES) {
        rbeg[gi1] = obase + ex + a;
        rend[gi1] = obase + ex + a + bq;
        ssrc[obase + ex + a] = gi1;
    }
    __syncthreads();

    for (int k = t; k < m; k += 256) {
        unsigned p = pairs[ibase + k];
        int dl = p >> 17;
        int idx = atomicAdd(&lcur[dl], 1);
        ssrc[obase + lofs[dl] + idx] = (int)(p & 0x1FFFF);
    }
}

// ---------------- layer 1 gather + softmax + ELU + fused node2 ----------
// One wave per dst. Quarter-wave = edge (eq=lane>>4), lane covers 4
// channels via one 8B dwordx2 load: 2.5 wave-instructions per edge.
// x2 unrolled (8 edges, 2 independent gather chains).
__global__ void __launch_bounds__(256) k_gather1(
        const int* __restrict__ rbeg, const int* __restrict__ rend,
        const int* __restrict__ ssrc, const float2* __restrict__ h1q,
        const __half* __restrict__ as1h, const float* __restrict__ ad1,
        const float* __restrict__ b1, const float* __restrict__ W2,
        const float* __restrict__ a_src2, const float* __restrict__ a_dst2,
        float4* __restrict__ rec) {
    int gtid = blockIdx.x * blockDim.x + threadIdx.x;
    int d    = gtid >> 6;
    int lane = threadIdx.x & 63;
    if (d >= N_NODES) return;
    int eq   = lane >> 4;      // edge slot within quad (0..3)
    int l    = lane & 15;      // channel-quad index (channels 4l..4l+3)
    int head = l >> 1;

    int beg = rbeg[d], end = rend[d];
    float adv = ad1[d * 8 + head];
    float a0 = 0.f, a1 = 0.f, a2 = 0.f, a3 = 0.f, den = 0.f;

    int k = beg;
    for (; k + 8 <= end; k += 8) {            // 2 independent quad chains
        int sA = ssrc[k + eq];
        int sB = ssrc[k + 4 + eq];
        float eA = __half2float(as1h[sA * 8 + head]);
        float eB = __half2float(as1h[sB * 8 + head]);
        float2 rA = h1q[(size_t)sA * 16 + l];
        float2 rB = h1q[(size_t)sB * 16 + l];
        float tA = eA + adv; tA = fmaxf(tA, NEG_SLOPE * tA);
        float tB = eB + adv; tB = fmaxf(tB, NEG_SLOPE * tB);
        float wA = __expf(tA), wB = __expf(tB);
        float2 fA0 = __half22float2(*(__half2*)&rA.x);
        float2 fA1 = __half22float2(*(__half2*)&rA.y);
        float2 fB0 = __half22float2(*(__half2*)&rB.x);
        float2 fB1 = __half22float2(*(__half2*)&rB.y);
        a0 += wA * fA0.x + wB * fB0.x;
        a1 += wA * fA0.y + wB * fB0.y;
        a2 += wA * fA1.x + wB * fB1.x;
        a3 += wA * fA1.y + wB * fB1.y;
        den += wA + wB;
    }
    for (; k < end; k += 4) {                  // masked tail quads
        int ki = k + eq;
        int s = ssrc[(ki < end) ? ki : beg];
        float e = __half2float(as1h[s * 8 + head]);
        float2 r = h1q[(size_t)s * 16 + l];
        float t = e + adv; t = fmaxf(t, NEG_SLOPE * t);
        float w = (ki < end) ? __expf(t) : 0.f;
        float2 f0 = __half22float2(*(__half2*)&r.x);
        float2 f1 = __half22float2(*(__half2*)&r.y);
        a0 += w * f0.x; a1 += w * f0.y;
        a2 += w * f1.x; a3 += w * f1.y;
        den += w;
    }
    // reduce across the 4 quarter-waves (all lanes end with totals)
    a0 += __shfl_xor(a0, 16, 64);  a0 += __shfl_xor(a0, 32, 64);
    a1 += __shfl_xor(a1, 16, 64);  a1 += __shfl_xor(a1, 32, 64);
    a2 += __shfl_xor(a2, 16, 64);  a2 += __shfl_xor(a2, 32, 64);
    a3 += __shfl_xor(a3, 16, 64);  a3 += __shfl_xor(a3, 32, 64);
    den += __shfl_xor(den, 16, 64); den += __shfl_xor(den, 32, 64);

    float inv = 1.f / den;                     // den>0 (self-loop guarantees)
    float4 bv = ((const float4*)b1)[l];
    float v0 = a0 * inv + bv.x;
    float v1 = a1 * inv + bv.y;
    float v2 = a2 * inv + bv.z;
    float v3 = a3 * inv + bv.w;
    v0 = (v0 > 0.f) ? v0 : (__expf(v0) - 1.f); // ELU
    v1 = (v1 > 0.f) ? v1 : (__expf(v1) - 1.f);
    v2 = (v2 > 0.f) ? v2 : (__expf(v2) - 1.f);
    v3 = (v3 > 0.f) ? v3 : (__expf(v3) - 1.f);

    // fused layer-2 transform: h2 = sum_c v_c * W2[c,:]
    float4 w2a = ((const float4*)W2)[2 * l];       // W2 rows 4l..4l+1
    float4 w2b = ((const float4*)W2)[2 * l + 1];   // W2 rows 4l+2..4l+3
    float h20 = v0 * w2a.x + v1 * w2a.z + v2 * w2b.x + v3 * w2b.z;
    float h21 = v0 * w2a.y + v1 * w2a.w + v2 * w2b.y + v3 * w2b.w;
#pragma unroll
    for (int off = 8; off; off >>= 1) {
        h20 += __shfl_xor(h20, off, 16);
        h21 += __shfl_xor(h21, off, 16);
    }
    if (lane == 0) {
        float as2v = h20 * a_src2[0] + h21 * a_src2[1];
        float ad2v = h20 * a_dst2[0] + h21 * a_dst2[1];
        rec[d] = make_float4(h20, h21, as2v, ad2v);
    }
}

// ---------------- layer 2: per-dst gather + log_softmax -----------------
__global__ void k_gather2(const int* __restrict__ rbeg, const int* __restrict__ rend,
                          const int* __restrict__ ssrc, const float4* __restrict__ rec,
                          const float* __restrict__ b2, float* __restrict__ out) {
    int gtid = blockIdx.x * blockDim.x + threadIdx.x;
    int d    = gtid >> 4;
    int lane = gtid & 15;
    if (d >= N_NODES) return;

    int beg = rbeg[d], end = rend[d];
    float adv = rec[d].w;
    float n0 = 0.f, n1 = 0.f, den = 0.f;
    int k = beg + lane;
    for (; k + 16 < end; k += 32) {
        int s0 = ssrc[k], s1 = ssrc[k + 16];
        float4 r0 = rec[s0];
        float4 r1 = rec[s1];
        float t0 = r0.z + adv; t0 = fmaxf(t0, NEG_SLOPE * t0);
        float t1 = r1.z + adv; t1 = fmaxf(t1, NEG_SLOPE * t1);
        float w0 = __expf(t0), w1 = __expf(t1);
        n0 += w0 * r0.x + w1 * r1.x;
        n1 += w0 * r0.y + w1 * r1.y;
        den += w0 + w1;
    }
    if (k < end) {
        int s = ssrc[k];
        float4 r = rec[s];
        float t = r.z + adv; t = fmaxf(t, NEG_SLOPE * t);
        float w = __expf(t);
        n0 += w * r.x; n1 += w * r.y; den += w;
    }
#pragma unroll
    for (int off = 8; off; off >>= 1) {
        n0  += __shfl_xor(n0,  off, 16);
        n1  += __shfl_xor(n1,  off, 16);
        den += __shfl_xor(den, off, 16);
    }
    if (lane == 0) {
        float o0 = n0 / den + b2[0];
        float o1 = n1 / den + b2[1];
        float m  = fmaxf(o0, o1);
        float lse = m + __logf(__expf(o0 - m) + __expf(o1 - m));
        out[d * 2 + 0] = o0 - lse;
        out[d * 2 + 1] = o1 - lse;
    }
}

extern "C" void kernel_launch(void* const* d_in, const int* in_sizes, int n_in,
                              void* d_out, int out_size, void* d_ws, size_t ws_size,
                              hipStream_t stream) {
    const float* x      = (const float*)d_in[0];
    const int*   ei     = (const int*)d_in[1];     // [2, E] int32
    const float* W1     = (const float*)d_in[2];
    const float* a_src1 = (const float*)d_in[3];
    const float* a_dst1 = (const float*)d_in[4];
    const float* b1     = (const float*)d_in[5];
    const float* W2     = (const float*)d_in[6];
    const float* a_src2 = (const float*)d_in[7];
    const float* a_dst2 = (const float*)d_in[8];
    const float* b2     = (const float*)d_in[9];
    float* out = (float*)d_out;

    const int* src = ei;
    const int* dst = ei + N_EDGES;

    // ---- workspace layout (~34 MB), everything fully written before read:
    // no memset required.
    int* cnt    = (int*)d_ws;                                   // NPB*NCB
    int* cb     = cnt + NPB * NCB;                              // NPB*NCB
    int* tots   = cb + NPB * NCB;                               // NCB
    int* bstart = tots + NCB;                                   // NCB
    int* rbeg   = bstart + NCB;                                 // N
    int* rend   = rbeg + N_NODES;                               // N
    unsigned* pairs = (unsigned*)(rend + N_NODES);              // E (6.4 MB)
    int* ssrc   = (int*)(pairs + N_EDGES);                      // E+N (6.8 MB)
    uintptr_t pp = ((uintptr_t)(ssrc + N_TOT) + 255) & ~(uintptr_t)255;
    float4*   rec  = (float4*)pp;                               // N float4
    float*    ad1  = (float*)(rec + N_NODES);                   // N*8 fp32
    __half*   h1h  = (__half*)(ad1 + (size_t)N_NODES * 8);      // N*64 fp16
    __half*   as1h = h1h + (size_t)N_NODES * 64;                // N*8 fp16

    k_node1<<<(N_NODES * 8 + 255) / 256, 256, 0, stream>>>(x, W1, a_src1, a_dst1,
                                                           h1h, as1h, ad1);
    k_partA<<<NPB, 256, 0, stream>>>(dst, cnt);
    k_s1<<<NCB, 256, 0, stream>>>(cnt, tots);
    k_s2<<<NCB, 512, 0, stream>>>(cnt, tots, cb, bstart);
    k_partB<<<NPB, 256, 0, stream>>>(src, dst, cb, pairs);
    k_scatter3<<<NCB, 256, 0, stream>>>(pairs, bstart, tots, rbeg, rend, ssrc);
    k_gather1<<<(N_NODES * 64 + 255) / 256, 256, 0, stream>>>(rbeg, rend, ssrc,
                                                              (const float2*)h1h,
                                                              as1h, ad1, b1, W2,
                                                              a_src2, a_dst2, rec);
    k_gather2<<<(N_NODES * 16 + 255) / 256, 256, 0, stream>>>(rbeg, rend, ssrc,
                                                              rec, b2, out);
}